// Round 6
// baseline (131.048 us; speedup 1.0000x reference)
//
#include <hip/hip_runtime.h>
#include <hip/hip_bf16.h>

#define B_    32
#define C_    128
#define L_    4096
#define P_    100
#define NPT   7            // p-tiles of 16 (P padded to 112)
#define Q_    20
#define NBIN  21
#define NCH   (NPT * 4)    // 28 A-frag chunks; chunk = pt*4 + ks
#define CHS   512          // shorts per chunk = 64 lanes * 8 bf16 (1 KB)
#define TPB   1024         // 16-wave blocks (R4)
#define LSPAN 512          // l-columns per block
#define HSZ   (P_ * NBIN)  // 2100 ints per histogram copy

typedef short          bf16x8 __attribute__((ext_vector_type(8)));
typedef float          f32x4  __attribute__((ext_vector_type(4)));
typedef unsigned short u16x8  __attribute__((ext_vector_type(8)));

__device__ inline unsigned short f2bf(float f) {
    __hip_bfloat16 h = __float2bfloat16(f);   // RNE
    unsigned short u; __builtin_memcpy(&u, &h, 2);
    return u;
}

// ---- prep: W (fp32 [P][C]) -> bf16 fragment lane order in d_ws ----
// Wf[chunk][lane][j], chunk=pt*4+ks: value = W[pt*16 + (lane&15)][ks*32 + (lane>>4)*8 + j]
// (rows p>=100 zeroed). Main kernel copies with plain dwordx4 -> conflict-free
// ds_read_b128 fragments.
__global__ void prep_w_kernel(const float* __restrict__ W, unsigned short* __restrict__ Wf) {
    const int t = blockIdx.x * 256 + threadIdx.x;     // 0 .. NCH*64-1
    if (t >= NCH * 64) return;
    const int chunk = t >> 6, lane = t & 63;
    const int pt = chunk >> 2, ks = chunk & 3;
    const int p  = pt * 16 + (lane & 15);
    const int c0 = ks * 32 + (lane >> 4) * 8;
    u16x8 v;
#pragma unroll
    for (int j = 0; j < 8; ++j)
        v[j] = (p < P_) ? f2bf(W[p * C_ + c0 + j]) : (unsigned short)0;
    *(u16x8*)(Wf + (size_t)t * 8) = v;                // 16B coalesced store
}

// ---- main: block = (b, 512-l span), 16 waves; wave owns 32 l (2 l-tiles) ----
// D[p][l] = sum_c W[p][c] * X[b][c][l] via mfma_f32_16x16x32_bf16.
//
// R5 changes:
//  (1) lt-SPLIT TWO-PASS PIPELINE (R3 idea, inline form — R3's regression was
//      scratch from pointer-param arrays, VGPR=64 + 54 MB spills). All arrays
//      are named locals with static indices. Pass A consumes only xv0 (first
//      32 issued loads; in-order vmcnt -> compiler emits partial waits), so
//      pass-A compute overlaps the in-flight xv1 loads. Cost: afrag ds_reads
//      double (28->56/wave) — LDS-pipe cheap vs the overlap bought.
//  (2) PER-QUAD HISTOGRAM COPIES hist[4][P*NBIN] (+25 KB LDS, 63 KB total,
//      still 1 block/CU): one atomic instruction scatters quads to disjoint
//      regions -> no intra-instruction same-address serialization (R4 profile:
//      1.04M bank-conflict cycles); banks (20*quad+21*nn+k)%32 near-uniform.
//      Epilogue sums 4 copies; counts still exact (sums <= 4096, x 2^-12).
//
// R4 (kept): 16-wave blocks, grid 8x32 — 4x fewer epilogue device-atomics and
// W-copies than 256-thread blocks. R2 (kept): swapped MFMA operands ->
// D row=l(quad*4+r), col=p(nn); algebra:
//   A'[m][k]=X[ks*32+k][l0+lt*16+m], B'[k][n]=W[pt*16+n][ks*32+k]
//   => D'[m][n] = a[b, p=pt*16+n, l=l0+lt*16+m]   (m89-verified C/D mapping)
//
// PHASE ORDER (prior-session post-mortem): __syncthreads drains vmcnt(0), so
// the ONLY pre-epilogue barrier (after W->LDS copy + hist zero) happens BEFORE
// any X load; afterwards each wave streams with no barrier.
__global__ __launch_bounds__(TPB, 4)
void radon_mfma6_kernel(const float* __restrict__ X, const unsigned short* __restrict__ Wf,
                        const float* __restrict__ minv, const float* __restrict__ maxv,
                        float* __restrict__ out) {
    __shared__ unsigned short Wlds[NCH * CHS];   // 28.0 KB
    __shared__ int   hist[4 * HSZ];              // 33.6 KB (per-quad copies)
    __shared__ float mn_s[P_], invd_s[P_];       // 0.8 KB

    const int tid  = threadIdx.x;
    const int b    = blockIdx.y;
    const int lblk = blockIdx.x;       // 0..7
    const int wave = tid >> 6;         // 0..15
    const int lane = tid & 63;
    const int quad = lane >> 4;
    const int nn   = lane & 15;

    // ---- Phase A: Wf -> LDS (plain dwordx4 copy), thresholds, hist zero, barrier.
    {
        const int4* src = (const int4*)Wf;
        int4* dst = (int4*)Wlds;
        for (int k = tid; k < NCH * 64; k += TPB)    // 1792 int4, L2-resident
            dst[k] = src[k];
    }
    for (int i = tid; i < P_; i += TPB) {
        const float mn = minv[i];
        mn_s[i]   = mn;
        invd_s[i] = (float)NBIN / (maxv[i] - mn);
    }
    for (int i = tid; i < 4 * HSZ; i += TPB) hist[i] = 0;
    __syncthreads();   // the ONLY barrier before the epilogue

    // ---- Phase B: issue ALL 64 X loads (xv0 first -> lower vmcnt slots).
    const int l0 = lblk * LSPAN + wave * 32;
    const float* Xb = X + (size_t)b * C_ * L_ + l0 + nn;
    float xv0[4][8], xv1[4][8];
#pragma unroll
    for (int ks = 0; ks < 4; ++ks)
#pragma unroll
        for (int j = 0; j < 8; ++j)
            xv0[ks][j] = Xb[(size_t)(ks * 32 + quad * 8 + j) * L_];
#pragma unroll
    for (int ks = 0; ks < 4; ++ks)
#pragma unroll
        for (int j = 0; j < 8; ++j)
            xv1[ks][j] = Xb[(size_t)(ks * 32 + quad * 8 + j) * L_ + 16];

    int* __restrict__ hq = &hist[quad * HSZ];

    // ==== Pass A: l-tile 0 (needs only first 32 loads; xv1 still in flight) ====
    bf16x8 bfrag0[4];
#pragma unroll
    for (int ks = 0; ks < 4; ++ks) {
        unsigned int u[4];
#pragma unroll
        for (int jp = 0; jp < 4; ++jp) {
            __hip_bfloat162 h2 = __float22bfloat162_rn(
                make_float2(xv0[ks][2 * jp], xv0[ks][2 * jp + 1]));
            __builtin_memcpy(&u[jp], &h2, 4);
        }
        __builtin_memcpy(&bfrag0[ks], u, 16);
    }
    for (int pt = 0; pt < NPT; ++pt) {
        bf16x8 a0 = *(const bf16x8*)(&Wlds[((pt * 4 + 0) * 64 + lane) * 8]);
        bf16x8 a1 = *(const bf16x8*)(&Wlds[((pt * 4 + 1) * 64 + lane) * 8]);
        bf16x8 a2 = *(const bf16x8*)(&Wlds[((pt * 4 + 2) * 64 + lane) * 8]);
        bf16x8 a3 = *(const bf16x8*)(&Wlds[((pt * 4 + 3) * 64 + lane) * 8]);
        f32x4 acc = {0.f, 0.f, 0.f, 0.f};
        acc = __builtin_amdgcn_mfma_f32_16x16x32_bf16(bfrag0[0], a0, acc, 0, 0, 0);
        acc = __builtin_amdgcn_mfma_f32_16x16x32_bf16(bfrag0[1], a1, acc, 0, 0, 0);
        acc = __builtin_amdgcn_mfma_f32_16x16x32_bf16(bfrag0[2], a2, acc, 0, 0, 0);
        acc = __builtin_amdgcn_mfma_f32_16x16x32_bf16(bfrag0[3], a3, acc, 0, 0, 0);
        const int p = pt * 16 + nn;          // per-thread constant within pt
        if (p < P_) {
            const float mn = mn_s[p], invd = invd_s[p];
#pragma unroll
            for (int r = 0; r < 4; ++r) {
                const float t = (acc[r] - mn) * invd;
                int k = 0;
                if (t > 0.f) { const int ki = (int)t; k = (ki > 20) ? 20 : ki; }
                atomicAdd(&hq[p * NBIN + k], 1);
            }
        }
    }

    // ==== Pass B: l-tile 1 ====
    bf16x8 bfrag1[4];
#pragma unroll
    for (int ks = 0; ks < 4; ++ks) {
        unsigned int u[4];
#pragma unroll
        for (int jp = 0; jp < 4; ++jp) {
            __hip_bfloat162 h2 = __float22bfloat162_rn(
                make_float2(xv1[ks][2 * jp], xv1[ks][2 * jp + 1]));
            __builtin_memcpy(&u[jp], &h2, 4);
        }
        __builtin_memcpy(&bfrag1[ks], u, 16);
    }
    for (int pt = 0; pt < NPT; ++pt) {
        bf16x8 a0 = *(const bf16x8*)(&Wlds[((pt * 4 + 0) * 64 + lane) * 8]);
        bf16x8 a1 = *(const bf16x8*)(&Wlds[((pt * 4 + 1) * 64 + lane) * 8]);
        bf16x8 a2 = *(const bf16x8*)(&Wlds[((pt * 4 + 2) * 64 + lane) * 8]);
        bf16x8 a3 = *(const bf16x8*)(&Wlds[((pt * 4 + 3) * 64 + lane) * 8]);
        f32x4 acc = {0.f, 0.f, 0.f, 0.f};
        acc = __builtin_amdgcn_mfma_f32_16x16x32_bf16(bfrag1[0], a0, acc, 0, 0, 0);
        acc = __builtin_amdgcn_mfma_f32_16x16x32_bf16(bfrag1[1], a1, acc, 0, 0, 0);
        acc = __builtin_amdgcn_mfma_f32_16x16x32_bf16(bfrag1[2], a2, acc, 0, 0, 0);
        acc = __builtin_amdgcn_mfma_f32_16x16x32_bf16(bfrag1[3], a3, acc, 0, 0, 0);
        const int p = pt * 16 + nn;
        if (p < P_) {
            const float mn = mn_s[p], invd = invd_s[p];
#pragma unroll
            for (int r = 0; r < 4; ++r) {
                const float t = (acc[r] - mn) * invd;
                int k = 0;
                if (t > 0.f) { const int ki = (int)t; k = (ki > 20) ? 20 : ki; }
                atomicAdd(&hq[p * NBIN + k], 1);
            }
        }
    }
    __syncthreads();

    // ---- Phase D: sum 4 copies + prefix-sum -> exact fp32 atomic accumulation
    for (int i = tid; i < P_ * Q_; i += TPB) {
        const int p  = i / Q_;
        const int qi = i - p * Q_;
        int s = 0;
        for (int k = 0; k <= qi; ++k) {
            const int idx = p * NBIN + k;
            s += hist[idx] + hist[HSZ + idx] + hist[2 * HSZ + idx] + hist[3 * HSZ + idx];
        }
        atomicAdd(&out[((size_t)b * P_ + p) * Q_ + qi], (float)s * (1.0f / (float)L_));
    }
}

extern "C" void kernel_launch(void* const* d_in, const int* in_sizes, int n_in,
                              void* d_out, int out_size, void* d_ws, size_t ws_size,
                              hipStream_t stream) {
    const float* X  = (const float*)d_in[0];
    const float* W  = (const float*)d_in[1];
    const float* mn = (const float*)d_in[2];
    const float* mx = (const float*)d_in[3];
    float* out = (float*)d_out;
    unsigned short* Wf = (unsigned short*)d_ws;   // needs NCH*64*16 = 28672 bytes

    hipMemsetAsync(out, 0, (size_t)out_size * sizeof(float), stream);
    prep_w_kernel<<<NCH * 64 / 256, 256, 0, stream>>>(W, Wf);

    dim3 grid(L_ / LSPAN, B_);
    radon_mfma6_kernel<<<grid, dim3(TPB), 0, stream>>>(X, Wf, mn, mx, out);
}

// Round 7
// 106.082 us; speedup vs baseline: 1.2353x; 1.2353x over previous
//
#include <hip/hip_runtime.h>
#include <hip/hip_bf16.h>

#define B_    32
#define C_    128
#define L_    4096
#define P_    100
#define NPT   7            // p-tiles of 16 (P padded to 112)
#define Q_    20
#define NBIN  21
#define NCH   (NPT * 4)    // 28 A-frag chunks; chunk = pt*4 + ks
#define CHS   512          // shorts per chunk = 64 lanes * 8 bf16 (1 KB)
#define TPB   1024         // 16-wave blocks (R4)
#define LSPAN 512          // l-columns per block
#define HSZ   (P_ * NBIN)

typedef short          bf16x8 __attribute__((ext_vector_type(8)));
typedef float          f32x4  __attribute__((ext_vector_type(4)));
typedef unsigned short u16x8  __attribute__((ext_vector_type(8)));

__device__ inline unsigned short f2bf(float f) {
    __hip_bfloat16 h = __float2bfloat16(f);   // RNE
    unsigned short u; __builtin_memcpy(&u, &h, 2);
    return u;
}

// ---- prep: W (fp32 [P][C]) -> bf16 fragment lane order in d_ws ----
// Wf[chunk][lane][j], chunk=pt*4+ks: value = W[pt*16 + (lane&15)][ks*32 + (lane>>4)*8 + j]
// (rows p>=100 zeroed). Main kernel copies with plain dwordx4 -> conflict-free
// ds_read_b128 fragments.
__global__ void prep_w_kernel(const float* __restrict__ W, unsigned short* __restrict__ Wf) {
    const int t = blockIdx.x * 256 + threadIdx.x;     // 0 .. NCH*64-1
    if (t >= NCH * 64) return;
    const int chunk = t >> 6, lane = t & 63;
    const int pt = chunk >> 2, ks = chunk & 3;
    const int p  = pt * 16 + (lane & 15);
    const int c0 = ks * 32 + (lane >> 4) * 8;
    u16x8 v;
#pragma unroll
    for (int j = 0; j < 8; ++j)
        v[j] = (p < P_) ? f2bf(W[p * C_ + c0 + j]) : (unsigned short)0;
    *(u16x8*)(Wf + (size_t)t * 8) = v;                // 16B coalesced store
}

// ---- main: block = (b, 512-l span), 16 waves; wave owns 32 l (2 l-tiles) ----
// D[p][l] = sum_c W[p][c] * X[b][c][l] via mfma_f32_16x16x32_bf16.
//
// R6 change: ks-OUTER STREAMING LOOP. R3/R5 both proved (VGPR=64 + 40-54 MB
// scratch WRITE_SIZE) that holding a raw fp32 l-tile live across a compute
// region spills. Here no fp32 tile ever outlives its stage: per ks-slice,
// issue NEXT slice's 16 loads (prefetch-1), cvt current slice to bf16, run
// 7 p-tiles x (1 ds_read_b128 + 2 MFMA) accumulating into acc[7][2] (56 regs,
// static indices via full unroll). sched_barrier(0) at stage top fences the
// load-clusterer: max ~32 fp32 live -> ~100 VGPR, <=128 cap from
// __launch_bounds__(1024,4) keeps the 16-wave block resident. Compute now
// interleaves INTO the 10.6 us X stream instead of running after it; only
// the bucket epilogue (~1 us) remains post-stream. ds_read count unchanged
// (28/wave, one afrag read per (pt,ks)).
//
// R5 post-mortem (evidence): per-quad hist split left SQ_LDS_BANK_CONFLICT
// unchanged (1.04M -> 1.03M) -> atomics' bank behavior is NOT the cost;
// reverted to single hist.
//
// R4 (kept): 16-wave blocks, grid 8x32 — 4x fewer epilogue device-atomics and
// W-copies than 256-thread blocks. R2 (kept): swapped MFMA operands ->
// D row=l(quad*4+r), col=p(nn); algebra:
//   A'[m][k]=X[ks*32+k][l0+lt*16+m], B'[k][n]=W[pt*16+n][ks*32+k]
//   => D'[m][n] = a[b, p=pt*16+n, l=l0+lt*16+m]   (m89-verified C/D mapping)
//
// PHASE ORDER (kept): the ONLY pre-epilogue barrier (after W->LDS copy + hist
// zero) happens BEFORE any X load; afterwards each wave streams with no
// barrier. Histogram: 21 uniform bins, prefix-sum epilogue, exact fp32
// atomicAdd (counts <= 4096, multiples of 2^-12 -> exact).
__global__ __launch_bounds__(TPB, 4)
void radon_mfma7_kernel(const float* __restrict__ X, const unsigned short* __restrict__ Wf,
                        const float* __restrict__ minv, const float* __restrict__ maxv,
                        float* __restrict__ out) {
    __shared__ unsigned short Wlds[NCH * CHS];   // 28.0 KB
    __shared__ int   hist[HSZ];                  // 8.4 KB
    __shared__ float mn_s[P_], invd_s[P_];       // 0.8 KB

    const int tid  = threadIdx.x;
    const int b    = blockIdx.y;
    const int lblk = blockIdx.x;       // 0..7
    const int wave = tid >> 6;         // 0..15
    const int lane = tid & 63;
    const int quad = lane >> 4;
    const int nn   = lane & 15;

    // ---- Phase A: Wf -> LDS (plain dwordx4 copy), thresholds, hist zero, barrier.
    {
        const int4* src = (const int4*)Wf;
        int4* dst = (int4*)Wlds;
        for (int k = tid; k < NCH * 64; k += TPB)    // 1792 int4, L2-resident
            dst[k] = src[k];
    }
    for (int i = tid; i < P_; i += TPB) {
        const float mn = minv[i];
        mn_s[i]   = mn;
        invd_s[i] = (float)NBIN / (maxv[i] - mn);
    }
    for (int i = tid; i < HSZ; i += TPB) hist[i] = 0;
    __syncthreads();   // the ONLY barrier before the epilogue

    // ---- Phase B+C fused: ks-outer stream. acc[pt][lt] live across all ks.
    const int l0 = lblk * LSPAN + wave * 32;
    const float* Xb = X + (size_t)b * C_ * L_ + l0 + nn;

    f32x4 acc0[NPT], acc1[NPT];
#pragma unroll
    for (int pt = 0; pt < NPT; ++pt) {
        acc0[pt] = (f32x4){0.f, 0.f, 0.f, 0.f};
        acc1[pt] = (f32x4){0.f, 0.f, 0.f, 0.f};
    }

    float xf[4][2][8];   // per-ks slice buffers; all indices static after unroll
    // prologue: issue ks=0's 16 loads
#pragma unroll
    for (int j = 0; j < 8; ++j) xf[0][0][j] = Xb[(size_t)(quad * 8 + j) * L_];
#pragma unroll
    for (int j = 0; j < 8; ++j) xf[0][1][j] = Xb[(size_t)(quad * 8 + j) * L_ + 16];

#pragma unroll
    for (int ks = 0; ks < 4; ++ks) {
        __builtin_amdgcn_sched_barrier(0);   // fence: no cross-stage load hoisting
        // prefetch next ks slice (16 loads) while this slice computes
        if (ks < 3) {
#pragma unroll
            for (int j = 0; j < 8; ++j)
                xf[ks + 1][0][j] = Xb[(size_t)((ks + 1) * 32 + quad * 8 + j) * L_];
#pragma unroll
            for (int j = 0; j < 8; ++j)
                xf[ks + 1][1][j] = Xb[(size_t)((ks + 1) * 32 + quad * 8 + j) * L_ + 16];
        }
        // cvt this slice (compiler waits vmcnt(16): prefetch stays in flight)
        bf16x8 b0, b1;
        {
            unsigned int u[4];
#pragma unroll
            for (int jp = 0; jp < 4; ++jp) {
                __hip_bfloat162 h2 = __float22bfloat162_rn(
                    make_float2(xf[ks][0][2 * jp], xf[ks][0][2 * jp + 1]));
                __builtin_memcpy(&u[jp], &h2, 4);
            }
            __builtin_memcpy(&b0, u, 16);
#pragma unroll
            for (int jp = 0; jp < 4; ++jp) {
                __hip_bfloat162 h2 = __float22bfloat162_rn(
                    make_float2(xf[ks][1][2 * jp], xf[ks][1][2 * jp + 1]));
                __builtin_memcpy(&u[jp], &h2, 4);
            }
            __builtin_memcpy(&b1, u, 16);
        }
        // 7 p-tiles: one afrag ds_read + 2 MFMA each
#pragma unroll
        for (int pt = 0; pt < NPT; ++pt) {
            bf16x8 a = *(const bf16x8*)(&Wlds[((pt * 4 + ks) * 64 + lane) * 8]);
            acc0[pt] = __builtin_amdgcn_mfma_f32_16x16x32_bf16(b0, a, acc0[pt], 0, 0, 0);
            acc1[pt] = __builtin_amdgcn_mfma_f32_16x16x32_bf16(b1, a, acc1[pt], 0, 0, 0);
        }
    }

    // ---- bucket epilogue: p = pt*16 + nn is per-thread constant per pt.
#pragma unroll
    for (int pt = 0; pt < NPT; ++pt) {
        const int p = pt * 16 + nn;
        if (p < P_) {
            const float mn = mn_s[p], invd = invd_s[p];
            int* __restrict__ hrow = &hist[p * NBIN];
#pragma unroll
            for (int r = 0; r < 4; ++r) {
                {
                    const float t = (acc0[pt][r] - mn) * invd;
                    int k = 0;
                    if (t > 0.f) { const int ki = (int)t; k = (ki > 20) ? 20 : ki; }
                    atomicAdd(&hrow[k], 1);
                }
                {
                    const float t = (acc1[pt][r] - mn) * invd;
                    int k = 0;
                    if (t > 0.f) { const int ki = (int)t; k = (ki > 20) ? 20 : ki; }
                    atomicAdd(&hrow[k], 1);
                }
            }
        }
    }
    __syncthreads();

    // ---- Phase D: prefix-sum histogram -> exact fp32 atomic accumulation
    for (int i = tid; i < P_ * Q_; i += TPB) {
        const int p  = i / Q_;
        const int qi = i - p * Q_;
        int s = 0;
        for (int k = 0; k <= qi; ++k) s += hist[p * NBIN + k];
        atomicAdd(&out[((size_t)b * P_ + p) * Q_ + qi], (float)s * (1.0f / (float)L_));
    }
}

extern "C" void kernel_launch(void* const* d_in, const int* in_sizes, int n_in,
                              void* d_out, int out_size, void* d_ws, size_t ws_size,
                              hipStream_t stream) {
    const float* X  = (const float*)d_in[0];
    const float* W  = (const float*)d_in[1];
    const float* mn = (const float*)d_in[2];
    const float* mx = (const float*)d_in[3];
    float* out = (float*)d_out;
    unsigned short* Wf = (unsigned short*)d_ws;   // needs NCH*64*16 = 28672 bytes

    hipMemsetAsync(out, 0, (size_t)out_size * sizeof(float), stream);
    prep_w_kernel<<<NCH * 64 / 256, 256, 0, stream>>>(W, Wf);

    dim3 grid(L_ / LSPAN, B_);
    radon_mfma7_kernel<<<grid, dim3(TPB), 0, stream>>>(X, Wf, mn, mx, out);
}

// Round 8
// 104.101 us; speedup vs baseline: 1.2588x; 1.0190x over previous
//
#include <hip/hip_runtime.h>
#include <hip/hip_bf16.h>

#define B_    32
#define C_    128
#define L_    4096
#define P_    100
#define NPT   7            // p-tiles of 16 (P padded to 112)
#define Q_    20
#define NBIN  21
#define HSTR  37           // R7: padded hist row stride (was 21): bank-collision
                           // condition strideΔnn+Δk≡0 mod 32 -> only Δnn=±13
#define NCH   (NPT * 4)    // 28 A-frag chunks; chunk = pt*4 + ks
#define CHS   512          // shorts per chunk = 64 lanes * 8 bf16 (1 KB)
#define TPB   1024         // 16-wave blocks (R4)
#define LSPAN 512          // l-columns per block

typedef short          bf16x8 __attribute__((ext_vector_type(8)));
typedef float          f32x4  __attribute__((ext_vector_type(4)));
typedef unsigned short u16x8  __attribute__((ext_vector_type(8)));

__device__ inline unsigned short f2bf(float f) {
    __hip_bfloat16 h = __float2bfloat16(f);   // RNE
    unsigned short u; __builtin_memcpy(&u, &h, 2);
    return u;
}

// ---- prep: W (fp32 [P][C]) -> bf16 fragment lane order in d_ws ----
// Wf[chunk][lane][j], chunk=pt*4+ks: value = W[pt*16 + (lane&15)][ks*32 + (lane>>4)*8 + j]
// (rows p>=100 zeroed). Main kernel copies with plain dwordx4 -> conflict-free
// ds_read_b128 fragments.
__global__ void prep_w_kernel(const float* __restrict__ W, unsigned short* __restrict__ Wf) {
    const int t = blockIdx.x * 256 + threadIdx.x;     // 0 .. NCH*64-1
    if (t >= NCH * 64) return;
    const int chunk = t >> 6, lane = t & 63;
    const int pt = chunk >> 2, ks = chunk & 3;
    const int p  = pt * 16 + (lane & 15);
    const int c0 = ks * 32 + (lane >> 4) * 8;
    u16x8 v;
#pragma unroll
    for (int j = 0; j < 8; ++j)
        v[j] = (p < P_) ? f2bf(W[p * C_ + c0 + j]) : (unsigned short)0;
    *(u16x8*)(Wf + (size_t)t * 8) = v;                // 16B coalesced store
}

// ---- main: block = (b, 512-l span), 16 waves; wave owns 32 l (2 l-tiles) ----
// D[p][l] = sum_c W[p][c] * X[b][c][l] via mfma_f32_16x16x32_bf16.
//
// R7: EXACT R4 STRUCTURE (verified 104.9) + two DS-pipe trims:
//  (1) hist row stride 21 -> 37: atomic same-bank condition 37Δnn+Δk≡0 (mod 32)
//      leaves only Δnn=±13 pairs (was Δnn=±3 with adjacent bins at stride 21,
//      frequent for Gaussian-concentrated bins). +6.4 KB LDS.
//  (2) Phase D two-step: per-p in-place prefix (100 threads x 21 adds), then
//      each output reads ONE LDS word (was ~11 avg) -> ~20k fewer lane-reads
//      on the shared DS pipe.
//
// Post-mortem ledger driving this: R3/R5 (lt-split pipeline) -> scratch spill
// (VGPR=64 + 40-54 MB WRITE_SIZE); R6 (ks-outer stream, spill-free) -> neutral
// (106.1); R0 4-blocks/CU -> +4 us of per-block overheads, no overlap. The
// load stream (~10.4 us, chip-BW-bound) and DS tail (~6 us) resist source-level
// overlap in this loop shape; remaining lever is DS-tail cost itself.
//
// R4 (kept): 16-wave blocks, grid 8x32. R2 (kept): swapped MFMA operands ->
// D row=l(quad*4+r), col=p(nn); algebra:
//   A'[m][k]=X[ks*32+k][l0+lt*16+m], B'[k][n]=W[pt*16+n][ks*32+k]
//   => D'[m][n] = a[b, p=pt*16+n, l=l0+lt*16+m]   (m89-verified C/D mapping)
//
// PHASE ORDER (kept): the ONLY pre-epilogue barrier happens BEFORE any X load;
// afterwards each wave streams loads -> cvt -> ds_read -> MFMA -> bucket with
// no barrier. Histogram: 21 uniform bins, prefix epilogue, exact fp32
// atomicAdd (counts <= 4096, multiples of 2^-12 -> exact).
__global__ __launch_bounds__(TPB, 4)
void radon_mfma8_kernel(const float* __restrict__ X, const unsigned short* __restrict__ Wf,
                        const float* __restrict__ minv, const float* __restrict__ maxv,
                        float* __restrict__ out) {
    __shared__ unsigned short Wlds[NCH * CHS];   // 28.0 KB
    __shared__ int   hist[P_ * HSTR];            // 14.8 KB (stride-37 rows)
    __shared__ float mn_s[P_], invd_s[P_];       // 0.8 KB

    const int tid  = threadIdx.x;
    const int b    = blockIdx.y;
    const int lblk = blockIdx.x;       // 0..7
    const int wave = tid >> 6;         // 0..15
    const int lane = tid & 63;
    const int quad = lane >> 4;
    const int nn   = lane & 15;

    // ---- Phase A: Wf -> LDS (plain dwordx4 copy), thresholds, hist zero, barrier.
    {
        const int4* src = (const int4*)Wf;
        int4* dst = (int4*)Wlds;
        for (int k = tid; k < NCH * 64; k += TPB)    // 1792 int4, L2-resident
            dst[k] = src[k];
    }
    for (int i = tid; i < P_; i += TPB) {
        const float mn = minv[i];
        mn_s[i]   = mn;
        invd_s[i] = (float)NBIN / (maxv[i] - mn);
    }
    for (int i = tid; i < P_ * HSTR; i += TPB) hist[i] = 0;
    __syncthreads();   // the ONLY barrier before the bucket epilogue

    // ---- Phase B: X loads + packed cvt (compiler interleaves, fine-grained vmcnt)
    const int l0 = lblk * LSPAN + wave * 32;
    const float* Xb = X + (size_t)b * C_ * L_;
    float xv[2][4][8];
#pragma unroll
    for (int lt = 0; lt < 2; ++lt)
#pragma unroll
        for (int ks = 0; ks < 4; ++ks)
#pragma unroll
            for (int j = 0; j < 8; ++j)
                xv[lt][ks][j] = Xb[(size_t)(ks * 32 + quad * 8 + j) * L_ + l0 + lt * 16 + nn];

    bf16x8 bfrag[2][4];
#pragma unroll
    for (int lt = 0; lt < 2; ++lt)
#pragma unroll
        for (int ks = 0; ks < 4; ++ks) {
            unsigned int u[4];
#pragma unroll
            for (int jp = 0; jp < 4; ++jp) {
                __hip_bfloat162 h2 = __float22bfloat162_rn(
                    make_float2(xv[lt][ks][2 * jp], xv[lt][ks][2 * jp + 1]));
                __builtin_memcpy(&u[jp], &h2, 4);
            }
            __builtin_memcpy(&bfrag[lt][ks], u, 16);
        }

    // ---- Phase C: 7 p-tiles, no barrier: ds_read W-frags + 8 MFMAs + bucket
    // p = pt*16 + nn is PER-THREAD CONSTANT within a pt iteration.
    for (int pt = 0; pt < NPT; ++pt) {
        bf16x8 afrag[4];
#pragma unroll
        for (int ks = 0; ks < 4; ++ks)
            afrag[ks] = *(const bf16x8*)(&Wlds[((pt * 4 + ks) * 64 + lane) * 8]);

        f32x4 acc0 = {0.f, 0.f, 0.f, 0.f};
        f32x4 acc1 = {0.f, 0.f, 0.f, 0.f};
#pragma unroll
        for (int ks = 0; ks < 4; ++ks) {
            // swapped operands: D row = l (quad*4+r), col = p (nn)
            acc0 = __builtin_amdgcn_mfma_f32_16x16x32_bf16(bfrag[0][ks], afrag[ks], acc0, 0, 0, 0);
            acc1 = __builtin_amdgcn_mfma_f32_16x16x32_bf16(bfrag[1][ks], afrag[ks], acc1, 0, 0, 0);
        }

        const int p = pt * 16 + nn;
        if (p < P_) {
            const float mn = mn_s[p], invd = invd_s[p];
            int* __restrict__ hrow = &hist[p * HSTR];
#pragma unroll
            for (int r = 0; r < 4; ++r) {
                {
                    const float t = (acc0[r] - mn) * invd;
                    int k = 0;
                    if (t > 0.f) { const int ki = (int)t; k = (ki > 20) ? 20 : ki; }
                    atomicAdd(&hrow[k], 1);
                }
                {
                    const float t = (acc1[r] - mn) * invd;
                    int k = 0;
                    if (t > 0.f) { const int ki = (int)t; k = (ki > 20) ? 20 : ki; }
                    atomicAdd(&hrow[k], 1);
                }
            }
        }
    }
    __syncthreads();

    // ---- Phase D step 1: in-place prefix per p (one thread per row)
    if (tid < P_) {
        int* row = &hist[tid * HSTR];
        int run = 0;
#pragma unroll
        for (int k = 0; k < NBIN; ++k) { run += row[k]; row[k] = run; }
    }
    __syncthreads();

    // ---- Phase D step 2: one LDS read per output -> exact fp32 atomic accumulation
    for (int i = tid; i < P_ * Q_; i += TPB) {
        const int p  = i / Q_;
        const int qi = i - p * Q_;
        const int s  = hist[p * HSTR + qi];   // prefix over bins 0..qi
        atomicAdd(&out[((size_t)b * P_ + p) * Q_ + qi], (float)s * (1.0f / (float)L_));
    }
}

extern "C" void kernel_launch(void* const* d_in, const int* in_sizes, int n_in,
                              void* d_out, int out_size, void* d_ws, size_t ws_size,
                              hipStream_t stream) {
    const float* X  = (const float*)d_in[0];
    const float* W  = (const float*)d_in[1];
    const float* mn = (const float*)d_in[2];
    const float* mx = (const float*)d_in[3];
    float* out = (float*)d_out;
    unsigned short* Wf = (unsigned short*)d_ws;   // needs NCH*64*16 = 28672 bytes

    hipMemsetAsync(out, 0, (size_t)out_size * sizeof(float), stream);
    prep_w_kernel<<<NCH * 64 / 256, 256, 0, stream>>>(W, Wf);

    dim3 grid(L_ / LSPAN, B_);
    radon_mfma8_kernel<<<grid, dim3(TPB), 0, stream>>>(X, Wf, mn, mx, out);
}

// Round 10
// 102.551 us; speedup vs baseline: 1.2779x; 1.0151x over previous
//
#include <hip/hip_runtime.h>
#include <hip/hip_bf16.h>

#define B_    32
#define C_    128
#define L_    4096
#define P_    100
#define NPT   7            // p-tiles of 16 (P padded to 112)
#define Q_    20
#define NBIN  21
#define HSTR  37           // R7: padded hist row stride: collision only at Δnn=±13
#define NCH   (NPT * 4)    // 28 A-frag chunks; chunk = pt*4 + ks
#define CHS   512          // shorts per chunk = 64 lanes * 8 bf16 (1 KB)
#define TPB   1024         // 16-wave blocks (R4)
#define LSPAN 512          // l-columns per block

typedef short          bf16x8 __attribute__((ext_vector_type(8)));
typedef float          f32x4  __attribute__((ext_vector_type(4)));
typedef unsigned short u16x8  __attribute__((ext_vector_type(8)));

__device__ inline unsigned short f2bf(float f) {
    __hip_bfloat16 h = __float2bfloat16(f);   // RNE
    unsigned short u; __builtin_memcpy(&u, &h, 2);
    return u;
}

// ---- prep: W (fp32 [P][C]) -> bf16 fragment lane order in d_ws ----
// Wf[chunk][lane][j], chunk=pt*4+ks: value = W[pt*16 + (lane&15)][ks*32 + (lane>>4)*8 + j]
// (rows p>=100 zeroed). Main kernel copies with plain dwordx4 -> conflict-free
// ds_read_b128 fragments.
__global__ void prep_w_kernel(const float* __restrict__ W, unsigned short* __restrict__ Wf) {
    const int t = blockIdx.x * 256 + threadIdx.x;     // 0 .. NCH*64-1
    if (t >= NCH * 64) return;
    const int chunk = t >> 6, lane = t & 63;
    const int pt = chunk >> 2, ks = chunk & 3;
    const int p  = pt * 16 + (lane & 15);
    const int c0 = ks * 32 + (lane >> 4) * 8;
    u16x8 v;
#pragma unroll
    for (int j = 0; j < 8; ++j)
        v[j] = (p < P_) ? f2bf(W[p * C_ + c0 + j]) : (unsigned short)0;
    *(u16x8*)(Wf + (size_t)t * 8) = v;                // 16B coalesced store
}

// ---- main: block = (b, 512-l span), 16 waves; wave owns 32 l ----
// D[p][l] = sum_c W[p][c] * X[b][c][l] via mfma_f32_16x16x32_bf16.
//
// R8 change: FULL-LINE dwordx2 X LOADS via lt-INTERLEAVE. The two l-tiles of a
// wave are now the EVEN and ODD columns of its 32-l span (tile0 = l0+2i,
// tile1 = l0+2i+1) instead of [0..15]/[16..31]. Lane nn loads float2 at
// l0+2nn: one instruction per (ks,j) covers 4 rows x 128 B FULL cache lines
// (was 2 instructions x 64 B halves) — 32 VMEM instr/thread instead of 64.
// Theory: the dword-granular 64 B request stream capped effective HBM BW at
// ~55-60% (observed ~2.6 TB/s during load phases; R6's prefetch was neutral
// because wave-TLP already overlaps the tail — the STREAM is the bottleneck).
// .x/.y are exactly the tile0/tile1 values; cvt is register-local; the MFMA
// only re-maps which l each acc element is — and the HISTOGRAM IS
// l-INDEPENDENT, so Phases C/D are unchanged. Identical value multiset =>
// identical absmax.
//
// R7 (kept): hist stride 37 (atomic bank spread) + two-step prefix epilogue.
// R4 (kept): 16-wave blocks, grid 8x32. R2 (kept): swapped MFMA operands ->
// D row=l-idx(quad*4+r), col=p(nn); algebra:
//   A'[m][k]=X[ks*32+k][l0+2m+lt], B'[k][n]=W[pt*16+n][ks*32+k]
//   => D'[m][n] = a[b, p=pt*16+n, l=l0+2*(quad*4+r)+lt]  (m89-verified C/D map)
//
// PHASE ORDER (kept): the ONLY pre-epilogue barrier happens BEFORE any X load;
// afterwards each wave streams loads -> cvt -> ds_read -> MFMA -> bucket with
// no barrier. Histogram: 21 uniform bins, prefix epilogue, exact fp32
// atomicAdd (counts <= 4096, multiples of 2^-12 -> exact).
__global__ __launch_bounds__(TPB, 4)
void radon_mfma9_kernel(const float* __restrict__ X, const unsigned short* __restrict__ Wf,
                        const float* __restrict__ minv, const float* __restrict__ maxv,
                        float* __restrict__ out) {
    __shared__ unsigned short Wlds[NCH * CHS];   // 28.0 KB
    __shared__ int   hist[P_ * HSTR];            // 14.8 KB (stride-37 rows)
    __shared__ float mn_s[P_], invd_s[P_];       // 0.8 KB

    const int tid  = threadIdx.x;
    const int b    = blockIdx.y;
    const int lblk = blockIdx.x;       // 0..7
    const int wave = tid >> 6;         // 0..15
    const int lane = tid & 63;
    const int quad = lane >> 4;
    const int nn   = lane & 15;

    // ---- Phase A: Wf -> LDS (plain dwordx4 copy), thresholds, hist zero, barrier.
    {
        const int4* src = (const int4*)Wf;
        int4* dst = (int4*)Wlds;
        for (int k = tid; k < NCH * 64; k += TPB)    // 1792 int4, L2-resident
            dst[k] = src[k];
    }
    for (int i = tid; i < P_; i += TPB) {
        const float mn = minv[i];
        mn_s[i]   = mn;
        invd_s[i] = (float)NBIN / (maxv[i] - mn);
    }
    for (int i = tid; i < P_ * HSTR; i += TPB) hist[i] = 0;
    __syncthreads();   // the ONLY barrier before the bucket epilogue

    // ---- Phase B: full-line float2 X loads + packed cvt.
    // lane nn covers columns l0w + 2nn (.x -> tile0) and l0w + 2nn + 1 (.y -> tile1)
    const int l0 = lblk * LSPAN + wave * 32;
    const float* Xb = X + (size_t)b * C_ * L_ + l0 + 2 * nn;
    float2 xv[4][8];
#pragma unroll
    for (int ks = 0; ks < 4; ++ks)
#pragma unroll
        for (int j = 0; j < 8; ++j)
            xv[ks][j] = *(const float2*)(Xb + (size_t)(ks * 32 + quad * 8 + j) * L_);

    bf16x8 bfrag[2][4];
#pragma unroll
    for (int ks = 0; ks < 4; ++ks) {
        unsigned int u0[4], u1[4];
#pragma unroll
        for (int jp = 0; jp < 4; ++jp) {
            __hip_bfloat162 h2;
            h2 = __float22bfloat162_rn(make_float2(xv[ks][2 * jp].x, xv[ks][2 * jp + 1].x));
            __builtin_memcpy(&u0[jp], &h2, 4);
            h2 = __float22bfloat162_rn(make_float2(xv[ks][2 * jp].y, xv[ks][2 * jp + 1].y));
            __builtin_memcpy(&u1[jp], &h2, 4);
        }
        __builtin_memcpy(&bfrag[0][ks], u0, 16);
        __builtin_memcpy(&bfrag[1][ks], u1, 16);
    }

    // ---- Phase C: 7 p-tiles, no barrier: ds_read W-frags + 8 MFMAs + bucket
    // p = pt*16 + nn is PER-THREAD CONSTANT within a pt iteration.
    for (int pt = 0; pt < NPT; ++pt) {
        bf16x8 afrag[4];
#pragma unroll
        for (int ks = 0; ks < 4; ++ks)
            afrag[ks] = *(const bf16x8*)(&Wlds[((pt * 4 + ks) * 64 + lane) * 8]);

        f32x4 acc0 = {0.f, 0.f, 0.f, 0.f};
        f32x4 acc1 = {0.f, 0.f, 0.f, 0.f};
#pragma unroll
        for (int ks = 0; ks < 4; ++ks) {
            // swapped operands: D row = l-index (quad*4+r), col = p (nn)
            acc0 = __builtin_amdgcn_mfma_f32_16x16x32_bf16(bfrag[0][ks], afrag[ks], acc0, 0, 0, 0);
            acc1 = __builtin_amdgcn_mfma_f32_16x16x32_bf16(bfrag[1][ks], afrag[ks], acc1, 0, 0, 0);
        }

        const int p = pt * 16 + nn;
        if (p < P_) {
            const float mn = mn_s[p], invd = invd_s[p];
            int* __restrict__ hrow = &hist[p * HSTR];
#pragma unroll
            for (int r = 0; r < 4; ++r) {
                {
                    const float t = (acc0[r] - mn) * invd;
                    int k = 0;
                    if (t > 0.f) { const int ki = (int)t; k = (ki > 20) ? 20 : ki; }
                    atomicAdd(&hrow[k], 1);
                }
                {
                    const float t = (acc1[r] - mn) * invd;
                    int k = 0;
                    if (t > 0.f) { const int ki = (int)t; k = (ki > 20) ? 20 : ki; }
                    atomicAdd(&hrow[k], 1);
                }
            }
        }
    }
    __syncthreads();

    // ---- Phase D step 1: in-place prefix per p (one thread per row)
    if (tid < P_) {
        int* row = &hist[tid * HSTR];
        int run = 0;
#pragma unroll
        for (int k = 0; k < NBIN; ++k) { run += row[k]; row[k] = run; }
    }
    __syncthreads();

    // ---- Phase D step 2: one LDS read per output -> exact fp32 atomic accumulation
    for (int i = tid; i < P_ * Q_; i += TPB) {
        const int p  = i / Q_;
        const int qi = i - p * Q_;
        const int s  = hist[p * HSTR + qi];   // prefix over bins 0..qi
        atomicAdd(&out[((size_t)b * P_ + p) * Q_ + qi], (float)s * (1.0f / (float)L_));
    }
}

extern "C" void kernel_launch(void* const* d_in, const int* in_sizes, int n_in,
                              void* d_out, int out_size, void* d_ws, size_t ws_size,
                              hipStream_t stream) {
    const float* X  = (const float*)d_in[0];
    const float* W  = (const float*)d_in[1];
    const float* mn = (const float*)d_in[2];
    const float* mx = (const float*)d_in[3];
    float* out = (float*)d_out;
    unsigned short* Wf = (unsigned short*)d_ws;   // needs NCH*64*16 = 28672 bytes

    hipMemsetAsync(out, 0, (size_t)out_size * sizeof(float), stream);
    prep_w_kernel<<<NCH * 64 / 256, 256, 0, stream>>>(W, Wf);

    dim3 grid(L_ / LSPAN, B_);
    radon_mfma9_kernel<<<grid, dim3(TPB), 0, stream>>>(X, Wf, mn, mx, out);
}